// Round 1
// baseline (373.609 us; speedup 1.0000x reference)
//
#include <hip/hip_runtime.h>
#include <hip/hip_bf16.h>

// Problem constants
#define B 2048
#define D 1024
#define H 64
#define K 3
#define SKIP 4
#define DOUT (D - SKIP)   // 1020
#define T 64              // number of D-chunks
#define DC (D / T)        // 16 dims per chunk

// Workspace layout (floats):
//   S/chk : T*B*H          = 8,388,608   (chunk sums, then scanned in place -> checkpoints)
//   Vp    : D*H*12         =   786,432   (packed V: [mean0..2, std0..2, alpha0..2, pad3])
//   Wt    : D*H            =    65,536   (W transposed to [d][h])
#define WS_S  0
#define WS_VP (T * B * H)
#define WS_WT (WS_VP + D * H * 12)

// ---------------------------------------------------------------------------
// Prep: transpose W -> Wt[d][h], pack V into Vp[d][h][12]
// ---------------------------------------------------------------------------
__global__ void k_pack(const float* __restrict__ W,
                       const float* __restrict__ Vm,
                       const float* __restrict__ Va,
                       const float* __restrict__ Vs,
                       float* __restrict__ Vp,
                       float* __restrict__ Wt) {
    int idx = blockIdx.x * 256 + threadIdx.x;  // 0 .. D*H-1, idx = d*64 + h
    if (idx >= D * H) return;
    int d = idx >> 6;
    int h = idx & 63;
    float* o = Vp + (size_t)idx * 12;
#pragma unroll
    for (int k = 0; k < 3; ++k) o[k]     = Vm[idx * 3 + k];
#pragma unroll
    for (int k = 0; k < 3; ++k) o[3 + k] = Vs[idx * 3 + k];
#pragma unroll
    for (int k = 0; k < 3; ++k) o[6 + k] = Va[idx * 3 + k];
    o[9] = 0.f; o[10] = 0.f; o[11] = 0.f;
    Wt[idx] = W[h * D + d];
}

// ---------------------------------------------------------------------------
// Pass 1: per-chunk partial sums  S[t][b][h] = sum_{d in chunk t} x[b,d]*W[h,d]
// One wave per (b, t); lane = h.
// ---------------------------------------------------------------------------
__global__ void k_sums(const float* __restrict__ x,
                       const float* __restrict__ Wt,
                       float* __restrict__ S) {
    int gw   = (blockIdx.x * 256 + threadIdx.x) >> 6;  // global wave id: 0 .. B*T-1
    int lane = threadIdx.x & 63;
    int b = gw >> 6;   // / T
    int t = gw & 63;   // % T
    float acc = 0.f;
    int dg0 = t * DC;
#pragma unroll
    for (int dl = 0; dl < DC; ++dl) {
        int dg = dg0 + dl;
        acc = fmaf(x[(size_t)b * D + dg], Wt[dg * H + lane], acc);
    }
    S[((size_t)t * B + b) * H + lane] = acc;
}

// ---------------------------------------------------------------------------
// Pass 2: exclusive scan over t (in place): S[t][b][h] <- c[h] + sum_{t'<t} S[t'][b][h]
// One thread per (b,h).
// ---------------------------------------------------------------------------
__global__ void k_scan(const float* __restrict__ c,
                       float* __restrict__ S) {
    int tid = blockIdx.x * 256 + threadIdx.x;  // 0 .. B*H-1, tid = b*64 + h
    if (tid >= B * H) return;
    int h = tid & 63;
    float run = c[h];
    float* p = S + tid;
#pragma unroll 4
    for (int t = 0; t < T; ++t) {
        float tmp = p[(size_t)t * (B * H)];
        p[(size_t)t * (B * H)] = run;
        run += tmp;
    }
}

// ---------------------------------------------------------------------------
// Pass 3 (main): one wave per (b-group of 64, chunk t). lane = b within group.
// Each lane keeps all 64 running accumulators a[h] in registers.
// Per d: emit outputs (using pre-update a), then a[h] += x[b,d]*W[h,d].
// ---------------------------------------------------------------------------
__global__ __launch_bounds__(64) void k_main(const float* __restrict__ x,
                                             const float* __restrict__ chk,
                                             const float* __restrict__ Vp,
                                             const float* __restrict__ Wt,
                                             const float* __restrict__ bm,
                                             const float* __restrict__ ba,
                                             const float* __restrict__ bs,
                                             float* __restrict__ out) {
    const int lane = threadIdx.x;      // 0..63
    const int bg   = blockIdx.x;       // 0..B/64-1
    const int t    = blockIdx.y;       // 0..T-1
    const int b    = bg * 64 + lane;

    // Load checkpoint state for this (b, t): 64 floats.
    float a[H];
    const float* cp = chk + ((size_t)t * B + b) * H;
#pragma unroll
    for (int h = 0; h < H; h += 4) {
        float4 v = *(const float4*)(cp + h);
        a[h] = v.x; a[h + 1] = v.y; a[h + 2] = v.z; a[h + 3] = v.w;
    }

    float* om = out + (size_t)b * DOUT * 3;
    float* os = om + (size_t)B * DOUT * 3;
    float* oa = os + (size_t)B * DOUT * 3;

    for (int dl = 0; dl < DC; ++dl) {
        const int dg = t * DC + dl;
        const float xv = x[(size_t)b * D + dg];

        if (dg >= SKIP) {
            const int i = dg - SKIP;
            float acc[9];
#pragma unroll
            for (int k = 0; k < 9; ++k) acc[k] = 0.f;

            const float* vp = Vp + (size_t)dg * (H * 12);
#pragma unroll
            for (int h = 0; h < H; ++h) {
                const float hv = fmaxf(a[h], 0.f);
                const float4 v0 = *(const float4*)(vp + h * 12);
                const float4 v1 = *(const float4*)(vp + h * 12 + 4);
                const float4 v2 = *(const float4*)(vp + h * 12 + 8);
                acc[0] = fmaf(hv, v0.x, acc[0]);
                acc[1] = fmaf(hv, v0.y, acc[1]);
                acc[2] = fmaf(hv, v0.z, acc[2]);
                acc[3] = fmaf(hv, v0.w, acc[3]);
                acc[4] = fmaf(hv, v1.x, acc[4]);
                acc[5] = fmaf(hv, v1.y, acc[5]);
                acc[6] = fmaf(hv, v1.z, acc[6]);
                acc[7] = fmaf(hv, v1.w, acc[7]);
                acc[8] = fmaf(hv, v2.x, acc[8]);
            }

            // mean = acc[0..2] + bmean[dg]
            om[(size_t)i * 3 + 0] = acc[0] + bm[dg * 3 + 0];
            om[(size_t)i * 3 + 1] = acc[1] + bm[dg * 3 + 1];
            om[(size_t)i * 3 + 2] = acc[2] + bm[dg * 3 + 2];

            // std = sigmoid(acc[3..5] + bstd[dg]) * 2 + 0.6
#pragma unroll
            for (int k = 0; k < 3; ++k) {
                float z = acc[3 + k] + bs[dg * 3 + k];
                os[(size_t)i * 3 + k] = 2.f / (1.f + __expf(-z)) + 0.6f;
            }

            // alpha = softmax(acc[6..8] + balpha[dg])
            {
                float z0 = acc[6] + ba[dg * 3 + 0];
                float z1 = acc[7] + ba[dg * 3 + 1];
                float z2 = acc[8] + ba[dg * 3 + 2];
                float mx = fmaxf(z0, fmaxf(z1, z2));
                float e0 = __expf(z0 - mx);
                float e1 = __expf(z1 - mx);
                float e2 = __expf(z2 - mx);
                float inv = 1.f / (e0 + e1 + e2);
                oa[(size_t)i * 3 + 0] = e0 * inv;
                oa[(size_t)i * 3 + 1] = e1 * inv;
                oa[(size_t)i * 3 + 2] = e2 * inv;
            }
        }

        // a[h] += x[b,dg] * W[h,dg]
        const float* wp = Wt + dg * H;
#pragma unroll
        for (int h = 0; h < H; h += 4) {
            float4 w = *(const float4*)(wp + h);
            a[h]     = fmaf(xv, w.x, a[h]);
            a[h + 1] = fmaf(xv, w.y, a[h + 1]);
            a[h + 2] = fmaf(xv, w.z, a[h + 2]);
            a[h + 3] = fmaf(xv, w.w, a[h + 3]);
        }
    }
}

// ---------------------------------------------------------------------------
extern "C" void kernel_launch(void* const* d_in, const int* in_sizes, int n_in,
                              void* d_out, int out_size, void* d_ws, size_t ws_size,
                              hipStream_t stream) {
    const float* x  = (const float*)d_in[0];   // [B, D]
    const float* W  = (const float*)d_in[1];   // [H, D]
    const float* c  = (const float*)d_in[2];   // [1, H]
    const float* Vm = (const float*)d_in[3];   // [D, H, K]
    const float* Va = (const float*)d_in[4];   // [D, H, K]
    const float* Vs = (const float*)d_in[5];   // [D, H, K]
    const float* bm = (const float*)d_in[6];   // [D, K]
    const float* ba = (const float*)d_in[7];   // [D, K]
    const float* bs = (const float*)d_in[8];   // [D, K]
    float* out = (float*)d_out;

    float* wsf = (float*)d_ws;
    float* S   = wsf + WS_S;   // chunk sums -> checkpoints (in place)
    float* Vp  = wsf + WS_VP;
    float* Wt  = wsf + WS_WT;

    // 1) pack V + transpose W
    k_pack<<<dim3((D * H + 255) / 256), dim3(256), 0, stream>>>(W, Vm, Va, Vs, Vp, Wt);
    // 2) per-chunk partial sums (one wave per (b,t))
    k_sums<<<dim3(B * T / 4), dim3(256), 0, stream>>>(x, Wt, S);
    // 3) scan over chunks -> checkpoints
    k_scan<<<dim3((B * H + 255) / 256), dim3(256), 0, stream>>>(c, S);
    // 4) main fused pass
    k_main<<<dim3(B / 64, T), dim3(64), 0, stream>>>(x, S, Vp, Wt, bm, ba, bs, out);
}

// Round 2
// 371.784 us; speedup vs baseline: 1.0049x; 1.0049x over previous
//
#include <hip/hip_runtime.h>
#include <hip/hip_bf16.h>

// Problem constants
#define B 2048
#define D 1024
#define H 64
#define K 3
#define SKIP 4
#define DOUT (D - SKIP)   // 1020
#define T 64              // number of D-chunks
#define DC (D / T)        // 16 dims per chunk

// Workspace layout (floats):
//   S   : T*B*H   = 8,388,608  (exclusive-scanned checkpoints, written by k_prefix)
//   Vp  : D*H*12  =   786,432  (packed V: [mean0..2, std0..2, alpha0..2, pad3])
//   Wt  : D*H     =    65,536  (W transposed to [d][h])
//   xT  : D*B     = 2,097,152  (x transposed to [d][b])
#define WS_S  0
#define WS_VP (T * B * H)
#define WS_WT (WS_VP + D * H * 12)
#define WS_XT (WS_WT + D * H)

// ---------------------------------------------------------------------------
// Prep: transpose W -> Wt[d][h], pack V into Vp[d][h][12]
// ---------------------------------------------------------------------------
__global__ __launch_bounds__(256) void k_pack(const float* __restrict__ W,
                                              const float* __restrict__ Vm,
                                              const float* __restrict__ Va,
                                              const float* __restrict__ Vs,
                                              float* __restrict__ Vp,
                                              float* __restrict__ Wt) {
    int idx = blockIdx.x * 256 + threadIdx.x;  // 0 .. D*H-1, idx = d*64 + h
    if (idx >= D * H) return;
    int d = idx >> 6;
    int h = idx & 63;
    float* o = Vp + (size_t)idx * 12;
#pragma unroll
    for (int k = 0; k < 3; ++k) o[k]     = Vm[idx * 3 + k];
#pragma unroll
    for (int k = 0; k < 3; ++k) o[3 + k] = Vs[idx * 3 + k];
#pragma unroll
    for (int k = 0; k < 3; ++k) o[6 + k] = Va[idx * 3 + k];
    o[9] = 0.f; o[10] = 0.f; o[11] = 0.f;
    Wt[idx] = W[h * D + d];
}

// ---------------------------------------------------------------------------
// Transpose x[B][D] -> xT[D][B] via 64x64 LDS tile
// grid (D/64, B/64), block 256
// ---------------------------------------------------------------------------
__global__ __launch_bounds__(256) void k_xt(const float* __restrict__ x,
                                            float* __restrict__ xT) {
    __shared__ float tile[64][65];
    const int tx = threadIdx.x & 63;
    const int ty = threadIdx.x >> 6;
    const int d0 = blockIdx.x * 64;
    const int b0 = blockIdx.y * 64;
#pragma unroll
    for (int r = 0; r < 64; r += 4)
        tile[r + ty][tx] = x[(size_t)(b0 + r + ty) * D + d0 + tx];
    __syncthreads();
#pragma unroll
    for (int r = 0; r < 64; r += 4)
        xT[(size_t)(d0 + r + ty) * B + b0 + tx] = tile[tx][r + ty];
}

// ---------------------------------------------------------------------------
// Fused prefix: one wave per b (lane = h). Walk all D dims sequentially,
// emitting exclusive checkpoints S[t][b][h] = c[h] + sum_{d < t*16} x[b,d]*W[h,d]
// every DC dims. Dependent-FMA chain is short (1024 x ~4cy ~ 1.7us).
// ---------------------------------------------------------------------------
__global__ __launch_bounds__(256) void k_prefix(const float* __restrict__ x,
                                                const float* __restrict__ Wt,
                                                const float* __restrict__ c,
                                                float* __restrict__ S) {
    const int lane = threadIdx.x & 63;
    const int w    = threadIdx.x >> 6;
    const int b    = blockIdx.x * 4 + w;
    float run = c[lane];
    const float* xr = x + (size_t)b * D;
    for (int t = 0; t < T; ++t) {
        S[((size_t)t * B + b) * H + lane] = run;
#pragma unroll
        for (int dl = 0; dl < DC; ++dl) {
            const int d = t * DC + dl;
            run = fmaf(xr[d], Wt[d * H + lane], run);
        }
    }
}

// ---------------------------------------------------------------------------
// Main pass helpers
// ---------------------------------------------------------------------------
__device__ __forceinline__ void half_step(
    int d0, int joff, int b,
    const float* __restrict__ xT, const float* __restrict__ Vp,
    const float* __restrict__ Wt, const float* __restrict__ bm,
    const float* __restrict__ ba, const float* __restrict__ bs,
    float a[H], float obm[24], float obs[24], float oba[24])
{
#pragma unroll
    for (int dl = 0; dl < 8; ++dl) {
        const int d = d0 + dl;
        const float xv = xT[(size_t)d * B + b];
        const int j = dl + joff;            // joff is a literal at each call site
        if (j >= 0) {
            float acc[9];
#pragma unroll
            for (int k = 0; k < 9; ++k) acc[k] = 0.f;
            const float* vp = Vp + (size_t)d * (H * 12);
#pragma unroll
            for (int h = 0; h < H; ++h) {
                const float hv = fmaxf(a[h], 0.f);
                const float4 v0 = *(const float4*)(vp + h * 12);
                const float4 v1 = *(const float4*)(vp + h * 12 + 4);
                const float4 v2 = *(const float4*)(vp + h * 12 + 8);
                acc[0] = fmaf(hv, v0.x, acc[0]);
                acc[1] = fmaf(hv, v0.y, acc[1]);
                acc[2] = fmaf(hv, v0.z, acc[2]);
                acc[3] = fmaf(hv, v0.w, acc[3]);
                acc[4] = fmaf(hv, v1.x, acc[4]);
                acc[5] = fmaf(hv, v1.y, acc[5]);
                acc[6] = fmaf(hv, v1.z, acc[6]);
                acc[7] = fmaf(hv, v1.w, acc[7]);
                acc[8] = fmaf(hv, v2.x, acc[8]);
            }
            // mean
            obm[j * 3 + 0] = acc[0] + bm[d * 3 + 0];
            obm[j * 3 + 1] = acc[1] + bm[d * 3 + 1];
            obm[j * 3 + 2] = acc[2] + bm[d * 3 + 2];
            // std = sigmoid(z)*2 + 0.6
#pragma unroll
            for (int k = 0; k < 3; ++k) {
                float z = acc[3 + k] + bs[d * 3 + k];
                obs[j * 3 + k] = 2.f * __builtin_amdgcn_rcpf(1.f + __expf(-z)) + 0.6f;
            }
            // alpha = softmax
            {
                float z0 = acc[6] + ba[d * 3 + 0];
                float z1 = acc[7] + ba[d * 3 + 1];
                float z2 = acc[8] + ba[d * 3 + 2];
                float mx = fmaxf(z0, fmaxf(z1, z2));
                float e0 = __expf(z0 - mx);
                float e1 = __expf(z1 - mx);
                float e2 = __expf(z2 - mx);
                float inv = __builtin_amdgcn_rcpf(e0 + e1 + e2);
                oba[j * 3 + 0] = e0 * inv;
                oba[j * 3 + 1] = e1 * inv;
                oba[j * 3 + 2] = e2 * inv;
            }
        }
        // a[h] += x[b,d] * W[h,d]
        const float* wp = Wt + d * H;
#pragma unroll
        for (int h = 0; h < H; h += 4) {
            float4 w = *(const float4*)(wp + h);
            a[h]     = fmaf(xv, w.x, a[h]);
            a[h + 1] = fmaf(xv, w.y, a[h + 1]);
            a[h + 2] = fmaf(xv, w.z, a[h + 2]);
            a[h + 3] = fmaf(xv, w.w, a[h + 3]);
        }
    }
}

__device__ __forceinline__ void flush3(float* __restrict__ dst, const float* buf, int nf4) {
#pragma unroll
    for (int q = 0; q < 6; ++q) {
        if (q < nf4) {
            float4 v = make_float4(buf[q * 4 + 0], buf[q * 4 + 1],
                                   buf[q * 4 + 2], buf[q * 4 + 3]);
            *(float4*)(dst + q * 4) = v;
        }
    }
}

// ---------------------------------------------------------------------------
// Pass 3 (main): one wave per (b-group of 64, chunk t). lane = b within group.
// Outputs buffered in registers per half-chunk (8 dims), flushed as float4 runs.
// ---------------------------------------------------------------------------
__global__ __launch_bounds__(64, 2) void k_main(const float* __restrict__ xT,
                                                const float* __restrict__ chk,
                                                const float* __restrict__ Vp,
                                                const float* __restrict__ Wt,
                                                const float* __restrict__ bm,
                                                const float* __restrict__ ba,
                                                const float* __restrict__ bs,
                                                float* __restrict__ out) {
    const int lane = threadIdx.x;      // 0..63
    const int bg   = blockIdx.x;       // 0..B/64-1
    const int t    = blockIdx.y;       // 0..T-1
    const int b    = bg * 64 + lane;

    // Load checkpoint state for this (b, t): 64 floats, per-lane contiguous.
    float a[H];
    const float* cp = chk + ((size_t)t * B + b) * H;
#pragma unroll
    for (int h = 0; h < H; h += 4) {
        float4 v = *(const float4*)(cp + h);
        a[h] = v.x; a[h + 1] = v.y; a[h + 2] = v.z; a[h + 3] = v.w;
    }

    float* om = out + (size_t)b * DOUT * 3;
    float* os = om + (size_t)B * DOUT * 3;
    float* oa = os + (size_t)B * DOUT * 3;

    float obm[24], obs[24], oba[24];

    if (t == 0) {
        // half 0: dims 0..7, emit dims 4..7 -> i = 0..3 (12 floats @ 0)
        half_step(0, -4, b, xT, Vp, Wt, bm, ba, bs, a, obm, obs, oba);
        flush3(om, obm, 3);
        flush3(os, obs, 3);
        flush3(oa, oba, 3);
        // half 1: dims 8..15 -> i = 4..11 (24 floats @ 12)
        half_step(8, 0, b, xT, Vp, Wt, bm, ba, bs, a, obm, obs, oba);
        flush3(om + 12, obm, 6);
        flush3(os + 12, obs, 6);
        flush3(oa + 12, oba, 6);
    } else {
        const int d0 = t * DC;
        // half 0: dims d0..d0+7 -> i start = d0-4
        half_step(d0, 0, b, xT, Vp, Wt, bm, ba, bs, a, obm, obs, oba);
        {
            const size_t off = (size_t)(d0 - 4) * 3;
            flush3(om + off, obm, 6);
            flush3(os + off, obs, 6);
            flush3(oa + off, oba, 6);
        }
        // half 1: dims d0+8..d0+15 -> i start = d0+4
        half_step(d0 + 8, 0, b, xT, Vp, Wt, bm, ba, bs, a, obm, obs, oba);
        {
            const size_t off = (size_t)(d0 + 4) * 3;
            flush3(om + off, obm, 6);
            flush3(os + off, obs, 6);
            flush3(oa + off, oba, 6);
        }
    }
}

// ---------------------------------------------------------------------------
extern "C" void kernel_launch(void* const* d_in, const int* in_sizes, int n_in,
                              void* d_out, int out_size, void* d_ws, size_t ws_size,
                              hipStream_t stream) {
    const float* x  = (const float*)d_in[0];   // [B, D]
    const float* W  = (const float*)d_in[1];   // [H, D]
    const float* c  = (const float*)d_in[2];   // [1, H]
    const float* Vm = (const float*)d_in[3];   // [D, H, K]
    const float* Va = (const float*)d_in[4];   // [D, H, K]
    const float* Vs = (const float*)d_in[5];   // [D, H, K]
    const float* bm = (const float*)d_in[6];   // [D, K]
    const float* ba = (const float*)d_in[7];   // [D, K]
    const float* bs = (const float*)d_in[8];   // [D, K]
    float* out = (float*)d_out;

    float* wsf = (float*)d_ws;
    float* S   = wsf + WS_S;
    float* Vp  = wsf + WS_VP;
    float* Wt  = wsf + WS_WT;
    float* xT  = wsf + WS_XT;

    // 1) pack V + transpose W
    k_pack<<<dim3((D * H + 255) / 256), dim3(256), 0, stream>>>(W, Vm, Va, Vs, Vp, Wt);
    // 2) transpose x
    k_xt<<<dim3(D / 64, B / 64), dim3(256), 0, stream>>>(x, xT);
    // 3) fused per-b prefix scan -> exclusive checkpoints
    k_prefix<<<dim3(B / 4), dim3(256), 0, stream>>>(x, Wt, c, S);
    // 4) main fused pass
    k_main<<<dim3(B / 64, T), dim3(64), 0, stream>>>(xT, S, Vp, Wt, bm, ba, bs, out);
}